// Round 2
// baseline (2100.627 us; speedup 1.0000x reference)
//
#include <hip/hip_runtime.h>

#define EPS_BN 1e-4f
constexpr int BLK = 256;
constexpr int CAPF = 8192;    // per-offset pair capacity, fine (expect ~1.4k)
constexpr int CAPC = 32768;   // coarse (expect ~10k)
constexpr int CAPD = 32768;   // down/up per-offset (expect ~12.5k)

// ---------- pair-list (rulebook) build ----------
__global__ __launch_bounds__(BLK) void build_pairs_k(
    const int* __restrict__ nbr, int n, int cap,
    int* __restrict__ cnt, int2* __restrict__ pairs,
    const int* __restrict__ parent, const int* __restrict__ offid,
    int capD, int* __restrict__ cntD, int2* __restrict__ pd, int2* __restrict__ pu) {
  int i = blockIdx.x * BLK + threadIdx.x;
  if (i >= n) return;
#pragma unroll 1
  for (int k = 0; k < 27; ++k) {
    if (k == 13) continue;
    int j = nbr[(size_t)i * 27 + k];
    if (j < 0) continue;
    int kk = k - (k > 13);
    int pos = atomicAdd(&cnt[kk], 1);
    if (pos < cap) pairs[(size_t)kk * cap + pos] = make_int2(j, i);
  }
  if (parent) {
    int o = offid[i], p = parent[i];
    int pos = atomicAdd(&cntD[o], 1);
    if (pos < capD) {
      pd[(size_t)o * capD + pos] = make_int2(i, p);
      pu[(size_t)o * capD + pos] = make_int2(p, i);
    }
  }
}

// ---------- generic pair GEMM tile: out[o] (+)= bnrelu(in[j]) @ W[k] ----------
// pairs==nullptr -> identity mode over n_ident rows, W already points at the k tile.
template <int CI, int CO, bool ATOMIC, bool BN, bool CAT>
__global__ __launch_bounds__(BLK) void pg_k(
    const float* __restrict__ inA, const float* __restrict__ inB,
    const int2* __restrict__ pairs, const int* __restrict__ cnts, int cap,
    int skip13, int n_ident,
    const float* __restrict__ stA, const float* __restrict__ stB,
    const float* __restrict__ W, float* __restrict__ out) {
  constexpr int GO = CO / 16;   // out cols per thread (2 or 4)
  constexpr int XP = 68;        // padded pair stride (16B-aligned rows, ~2-way banks)
  __shared__ float lw[CI * CO];
  __shared__ float lx[CI * XP];
  __shared__ int lin[64], lout[64];
  int t = threadIdx.x;
  int k = blockIdx.y;
  int cnt = pairs ? min(cnts[k], cap) : n_ident;
  int base = blockIdx.x * 64;
  if (base >= cnt) return;
  int wk = pairs ? (k + (skip13 && k >= 13)) : 0;

  if (t < 64) {
    int gi = base + t;
    int2 pr = make_int2(-1, -1);
    if (gi < cnt) pr = pairs ? pairs[(size_t)k * cap + gi] : make_int2(gi, gi);
    lin[t] = pr.x;
    lout[t] = pr.y;
  }
  const float* wsrc = W + (size_t)wk * (CI * CO);
  for (int idx = t; idx < CI * CO / 4; idx += BLK)
    *reinterpret_cast<float4*>(&lw[idx * 4]) = reinterpret_cast<const float4*>(wsrc)[idx];
  __syncthreads();

  if constexpr (CI == 3) {
    for (int idx = t; idx < 64 * 3; idx += BLK) {
      int r = idx & 63, c = idx >> 6;
      int j = lin[r];
      lx[c * XP + r] = (j >= 0) ? inA[(size_t)j * 3 + c] : 0.f;
    }
  } else {
    constexpr int C4 = CI / 4;
    for (int idx = t; idx < 64 * C4; idx += BLK) {
      int r = idx / C4, c4 = idx - r * C4;
      int j = lin[r];
      float v[4] = {0.f, 0.f, 0.f, 0.f};
      int cb = c4 * 4;
      if (j >= 0) {
        if constexpr (CAT) {
          constexpr int H4 = C4 / 2;
          const float* src;
          const float* st;
          int cc;
          if (c4 < H4) { src = inA; st = stA; cc = cb; }
          else         { src = inB; st = stB; cc = cb - CI / 2; }
          float4 x = *reinterpret_cast<const float4*>(src + (size_t)j * (CI / 2) + cc);
          v[0] = x.x; v[1] = x.y; v[2] = x.z; v[3] = x.w;
#pragma unroll
          for (int q = 0; q < 4; ++q) {
            float y = fmaf(v[q], st[cc + q], st[CI / 2 + cc + q]);
            v[q] = y > 0.f ? y : 0.f;
          }
        } else {
          float4 x = *reinterpret_cast<const float4*>(inA + (size_t)j * CI + cb);
          v[0] = x.x; v[1] = x.y; v[2] = x.z; v[3] = x.w;
          if constexpr (BN) {
#pragma unroll
            for (int q = 0; q < 4; ++q) {
              float y = fmaf(v[q], stA[cb + q], stA[CI + cb + q]);
              v[q] = y > 0.f ? y : 0.f;
            }
          }
        }
      }
#pragma unroll
      for (int q = 0; q < 4; ++q) lx[(cb + q) * XP + r] = v[q];
    }
  }
  __syncthreads();

  int p4 = (t & 15) * 4;
  int g = (t >> 4) * GO;
  float acc[4][GO];
#pragma unroll
  for (int a = 0; a < 4; ++a)
#pragma unroll
    for (int b = 0; b < GO; ++b) acc[a][b] = 0.f;
#pragma unroll
  for (int c = 0; c < CI; ++c) {
    float4 xv = *reinterpret_cast<const float4*>(&lx[c * XP + p4]);
    float xs[4] = {xv.x, xv.y, xv.z, xv.w};
    float wv[GO];
    if constexpr (GO == 4) {
      float4 w4 = *reinterpret_cast<const float4*>(&lw[c * CO + g]);
      wv[0] = w4.x; wv[1] = w4.y; wv[2] = w4.z; wv[3] = w4.w;
    } else {
      float2 w2 = *reinterpret_cast<const float2*>(&lw[c * CO + g]);
      wv[0] = w2.x; wv[1] = w2.y;
    }
#pragma unroll
    for (int a = 0; a < 4; ++a)
#pragma unroll
      for (int b = 0; b < GO; ++b) acc[a][b] = fmaf(xs[a], wv[b], acc[a][b]);
  }
#pragma unroll
  for (int a = 0; a < 4; ++a) {
    int o = lout[p4 + a];
    if (o < 0) continue;
    float* ob = out + (size_t)o * CO + g;
    if constexpr (ATOMIC) {
#pragma unroll
      for (int b = 0; b < GO; ++b) atomicAdd(ob + b, acc[a][b]);
    } else {
      if constexpr (GO == 4)
        *reinterpret_cast<float4*>(ob) = make_float4(acc[a][0], acc[a][1], acc[a][2], acc[a][3]);
      else
        *reinterpret_cast<float2*>(ob) = make_float2(acc[a][0], acc[a][1]);
    }
  }
}

// ---------------- per-channel sum / sumsq ----------------
template <int C>
__global__ __launch_bounds__(BLK) void stats_k(
    const float* __restrict__ f, int n, float* __restrict__ sums) {
  constexpr int G = BLK / C;
  int c = threadIdx.x % C;
  int g = threadIdx.x / C;
  float s = 0.f, ss = 0.f;
  for (int r = blockIdx.x * G + g; r < n; r += gridDim.x * G) {
    float x = f[(size_t)r * C + c];
    s += x;
    ss += x * x;
  }
  __shared__ float ls[BLK], lss[BLK];
  ls[threadIdx.x] = s;
  lss[threadIdx.x] = ss;
  __syncthreads();
  if (threadIdx.x < C) {
    float ts = 0.f, tss = 0.f;
#pragma unroll
    for (int q = 0; q < G; ++q) { ts += ls[q * C + c]; tss += lss[q * C + c]; }
    atomicAdd(&sums[c], ts);
    atomicAdd(&sums[C + c], tss);
  }
}

__global__ void finalize_k(const float* __restrict__ sums,
                           const float* __restrict__ gamma,
                           const float* __restrict__ beta, float inv_n,
                           float* __restrict__ st, int C) {
  int c = threadIdx.x;
  if (c >= C) return;
  float mu = sums[c] * inv_n;
  float var = sums[C + c] * inv_n - mu * mu;
  float sc = gamma[c] / sqrtf(var + EPS_BN);
  st[c] = sc;
  st[C + c] = beta[c] - mu * sc;
}

// ---------------- head: bn(f3) @ w_lin + b_lin -> [N,50] ----------------
__global__ __launch_bounds__(BLK) void head_k(
    const float* __restrict__ fin, const float* __restrict__ st,
    const float* __restrict__ Wl, const float* __restrict__ bl,
    float* __restrict__ out, int n) {
  __shared__ float lw[32 * 50];
  __shared__ float lb[52];
  for (int idx = threadIdx.x; idx < 1600; idx += BLK) lw[idx] = Wl[idx];
  if (threadIdx.x < 50) lb[threadIdx.x] = bl[threadIdx.x];
  __syncthreads();
  int i = blockIdx.x * BLK + threadIdx.x;
  if (i >= n) return;
  float x[32];
  const float* fj = fin + (size_t)i * 32;
#pragma unroll
  for (int c4 = 0; c4 < 8; ++c4) {
    float4 v = *reinterpret_cast<const float4*>(fj + c4 * 4);
    float vs[4] = {v.x, v.y, v.z, v.w};
#pragma unroll
    for (int q = 0; q < 4; ++q) {
      int c = c4 * 4 + q;
      float y = fmaf(vs[q], st[c], st[32 + c]);
      x[c] = y > 0.f ? y : 0.f;
    }
  }
  float acc[50];
#pragma unroll
  for (int co = 0; co < 50; ++co) acc[co] = lb[co];
#pragma unroll 4
  for (int c = 0; c < 32; ++c) {
#pragma unroll
    for (int co = 0; co < 50; ++co) acc[co] = fmaf(x[c], lw[c * 50 + co], acc[co]);
  }
  float* o = out + (size_t)i * 50;
#pragma unroll
  for (int co = 0; co < 25; ++co)
    *reinterpret_cast<float2*>(o + co * 2) = make_float2(acc[co * 2], acc[co * 2 + 1]);
}

extern "C" void kernel_launch(void* const* d_in, const int* in_sizes, int n_in,
                              void* d_out, int out_size, void* d_ws, size_t ws_size,
                              hipStream_t stream) {
  const float* feat   = (const float*)d_in[1];
  const int*   nbrF   = (const int*)d_in[2];
  const int*   nbrC   = (const int*)d_in[3];
  const int*   parent = (const int*)d_in[4];
  const int*   offid  = (const int*)d_in[5];
  const float* w_in   = (const float*)d_in[7];
  const float* w_b1   = (const float*)d_in[8];
  const float* w_down = (const float*)d_in[9];
  const float* w_b2   = (const float*)d_in[10];
  const float* w_up   = (const float*)d_in[11];
  const float* w_b3   = (const float*)d_in[12];
  const float* g1 = (const float*)d_in[13], *b1 = (const float*)d_in[14];
  const float* gd = (const float*)d_in[15], *bd = (const float*)d_in[16];
  const float* g2 = (const float*)d_in[17], *b2 = (const float*)d_in[18];
  const float* gu = (const float*)d_in[19], *bu = (const float*)d_in[20];
  const float* g3 = (const float*)d_in[21], *b3 = (const float*)d_in[22];
  const float* go = (const float*)d_in[23], *bo = (const float*)d_in[24];
  const float* w_lin = (const float*)d_in[25];
  const float* b_lin = (const float*)d_in[26];
  float* out = (float*)d_out;

  int N  = in_sizes[4];
  int NC = in_sizes[3] / 27;

  size_t szF = (size_t)N * 32;
  size_t szG = (size_t)NC * 64;

  float* ws  = (float*)d_ws;
  float* f1  = ws;              // [N,32]; reused as f3
  float* f2  = f1 + szF;        // [N,32] skip
  float* gC  = f2 + szF;        // [NC,64]; reused as u [N,32]
  float* g2c = gC + szG;        // [NC,64]
  float* sums1 = g2c + szG;     // 64
  float* sumsD = sums1 + 64;    // 64
  float* sums2 = sumsD + 64;    // 128
  float* sumsU = sums2 + 128;   // 128
  float* sums4 = sumsU + 128;   // 64
  float* sums5 = sums4 + 64;    // 64
  float* st1  = sums5 + 64;
  float* stD  = st1 + 64;
  float* st3a = stD + 64;
  float* st2  = st3a + 64;      // 128
  float* stU  = st2 + 128;      // 128
  float* st3b = stU + 128;      // 64
  float* stO  = st3b + 64;      // 64
  int* cntF = (int*)(stO + 64);             // 26
  int* cntC = cntF + 26;                    // 26
  int* cntD = cntC + 26;                    // 8 (+4 pad)
  int2* pf = (int2*)(((uintptr_t)(cntD + 12) + 15) & ~(uintptr_t)15);  // [26,CAPF]
  int2* pc = pf + (size_t)26 * CAPF;        // [26,CAPC]
  int2* pd = pc + (size_t)26 * CAPC;        // [8,CAPD]
  int2* pu = pd + (size_t)8 * CAPD;         // [8,CAPD]

  hipMemsetAsync(sums1, 0, 512 * sizeof(float), stream);
  hipMemsetAsync(cntF, 0, 64 * sizeof(int), stream);
  hipMemsetAsync(gC, 0, szG * sizeof(float), stream);

  int gridN = (N + BLK - 1) / BLK;
  int gridC = (NC + BLK - 1) / BLK;
  int tN = (N + 63) / 64, tC = (NC + 63) / 64;
  int sgrid = 304;
  float invN = 1.f / (float)N, invC = 1.f / (float)NC;

  build_pairs_k<<<gridN, BLK, 0, stream>>>(nbrF, N, CAPF, cntF, pf,
                                           parent, offid, CAPD, cntD, pd, pu);
  build_pairs_k<<<gridC, BLK, 0, stream>>>(nbrC, NC, CAPC, cntC, pc,
                                           nullptr, nullptr, 0, nullptr, nullptr, nullptr);

  // conv_in: dense self + sparse others -> f1
  pg_k<3, 32, false, false, false><<<dim3(tN, 1), BLK, 0, stream>>>(
      feat, nullptr, nullptr, nullptr, 0, 0, N, nullptr, nullptr, w_in + 13 * 96, f1);
  pg_k<3, 32, true, false, false><<<dim3(CAPF / 64, 26), BLK, 0, stream>>>(
      feat, nullptr, pf, cntF, CAPF, 1, 0, nullptr, nullptr, w_in, f1);
  stats_k<32><<<sgrid, BLK, 0, stream>>>(f1, N, sums1);
  finalize_k<<<1, 64, 0, stream>>>(sums1, g1, b1, invN, st1, 32);

  // b1 -> f2
  pg_k<32, 32, false, true, false><<<dim3(tN, 1), BLK, 0, stream>>>(
      f1, nullptr, nullptr, nullptr, 0, 0, N, st1, nullptr, w_b1 + 13 * 1024, f2);
  pg_k<32, 32, true, true, false><<<dim3(CAPF / 64, 26), BLK, 0, stream>>>(
      f1, nullptr, pf, cntF, CAPF, 1, 0, st1, nullptr, w_b1, f2);
  stats_k<32><<<sgrid, BLK, 0, stream>>>(f2, N, sumsD);
  finalize_k<<<1, 64, 0, stream>>>(sumsD, gd, bd, invN, stD, 32);
  finalize_k<<<1, 64, 0, stream>>>(sumsD, g3, b3, invN, st3a, 32);

  // down -> gC (memset above)
  pg_k<32, 64, true, true, false><<<dim3(CAPD / 64, 8), BLK, 0, stream>>>(
      f2, nullptr, pd, cntD, CAPD, 0, 0, stD, nullptr, w_down, gC);
  stats_k<64><<<sgrid, BLK, 0, stream>>>(gC, NC, sums2);
  finalize_k<<<1, 64, 0, stream>>>(sums2, g2, b2, invC, st2, 64);

  // b2 -> g2c
  pg_k<64, 64, false, true, false><<<dim3(tC, 1), BLK, 0, stream>>>(
      gC, nullptr, nullptr, nullptr, 0, 0, NC, st2, nullptr, w_b2 + 13 * 4096, g2c);
  pg_k<64, 64, true, true, false><<<dim3(CAPC / 64, 26), BLK, 0, stream>>>(
      gC, nullptr, pc, cntC, CAPC, 1, 0, st2, nullptr, w_b2, g2c);
  stats_k<64><<<sgrid, BLK, 0, stream>>>(g2c, NC, sumsU);
  finalize_k<<<1, 64, 0, stream>>>(sumsU, gu, bu, invC, stU, 64);

  // up -> u (reuse gC region; plain stores cover every fine row exactly once)
  float* u = gC;
  pg_k<64, 32, false, true, false><<<dim3(CAPD / 64, 8), BLK, 0, stream>>>(
      g2c, nullptr, pu, cntD, CAPD, 0, 0, stU, nullptr, w_up, u);
  stats_k<32><<<sgrid, BLK, 0, stream>>>(u, N, sums4);
  finalize_k<<<1, 64, 0, stream>>>(sums4, g3 + 32, b3 + 32, invN, st3b, 32);

  // b3 (concat) -> f3 (reuse f1)
  float* f3 = f1;
  pg_k<64, 32, false, true, true><<<dim3(tN, 1), BLK, 0, stream>>>(
      f2, u, nullptr, nullptr, 0, 0, N, st3a, st3b, w_b3 + 13 * 2048, f3);
  pg_k<64, 32, true, true, true><<<dim3(CAPF / 64, 26), BLK, 0, stream>>>(
      f2, u, pf, cntF, CAPF, 1, 0, st3a, st3b, w_b3, f3);
  stats_k<32><<<sgrid, BLK, 0, stream>>>(f3, N, sums5);
  finalize_k<<<1, 64, 0, stream>>>(sums5, go, bo, invN, stO, 32);

  head_k<<<gridN, BLK, 0, stream>>>(f3, stO, w_lin, b_lin, out, N);
}

// Round 3
// 566.824 us; speedup vs baseline: 3.7060x; 3.7060x over previous
//
#include <hip/hip_runtime.h>

#define EPS_BN 1e-4f
constexpr int BLK = 256;
constexpr int ECAPF = 256;   // fine tile pair cap (self 64 + ~24 expected non-self)
constexpr int ECAPC = 640;   // coarse tile pair cap (~242 expected)

// ---------- rulebook build: per 64-row output tile, pairs grouped by k ----------
// 64 threads = 1 wave per block. entry = (r<<25) | j
__global__ __launch_bounds__(64) void build_subm_k(
    const int* __restrict__ nbr, int n, int ecap,
    int* __restrict__ seg, int* __restrict__ ent) {
  int T = blockIdx.x, r = threadIdx.x;
  int i = T * 64 + r;
  bool valid = i < n;
  int base = 0;
  if (r == 0) seg[T * 28] = 0;
#pragma unroll 1
  for (int k = 0; k < 27; ++k) {
    int j = valid ? nbr[(size_t)i * 27 + k] : -1;
    bool act = j >= 0;
    unsigned long long mb = __ballot(act);
    int pre = __popcll(mb & ((1ull << r) - 1));
    if (act && base + pre < ecap)
      ent[(size_t)T * ecap + base + pre] = (r << 25) | j;
    base += __popcll(mb);
    if (r == 0) seg[T * 28 + k + 1] = base;
  }
}

// per-parent child slot assignment (int atomics only)
__global__ __launch_bounds__(BLK) void child_scatter_k(
    const int* __restrict__ parent, const int* __restrict__ offid, int n,
    int* __restrict__ ccnt, int* __restrict__ cent) {
  int i = blockIdx.x * BLK + threadIdx.x;
  if (i >= n) return;
  int p = parent[i];
  int slot = atomicAdd(&ccnt[p], 1);
  cent[p * 8 + slot] = i | (offid[i] << 25);
}

// down rulebook: per coarse tile, children grouped by offset o (rows unique per o)
__global__ __launch_bounds__(64) void build_down_k(
    const int* __restrict__ ccnt, const int* __restrict__ cent, int nc,
    int* __restrict__ segd, int* __restrict__ entd) {
  int T = blockIdx.x, r = threadIdx.x;
  int p = T * 64 + r;
  bool valid = p < nc;
  int cn = valid ? ccnt[p] : 0;
  int e[8];
#pragma unroll
  for (int s = 0; s < 8; ++s) e[s] = s < cn ? cent[p * 8 + s] : -1;
  int base = 0;
  if (r == 0) segd[T * 9] = 0;
#pragma unroll 1
  for (int oo = 0; oo < 8; ++oo) {
#pragma unroll
    for (int s = 0; s < 8; ++s) {
      bool act = e[s] >= 0 && (e[s] >> 25) == oo;
      unsigned long long mb = __ballot(act);
      int pre = __popcll(mb & ((1ull << r) - 1));
      if (act) entd[(size_t)T * 512 + base + pre] = (r << 25) | (e[s] & 0x1FFFFFF);
      base += __popcll(mb);
    }
    if (r == 0) segd[T * 9 + oo + 1] = base;
  }
}

// up rulebook: per fine tile, rows grouped by own offset o; j = parent
__global__ __launch_bounds__(64) void build_up_k(
    const int* __restrict__ parent, const int* __restrict__ offid, int n,
    int* __restrict__ segu, int* __restrict__ entu) {
  int T = blockIdx.x, r = threadIdx.x;
  int i = T * 64 + r;
  bool valid = i < n;
  int o = valid ? offid[i] : -1;
  int pa = valid ? parent[i] : 0;
  int base = 0;
  if (r == 0) segu[T * 9] = 0;
#pragma unroll 1
  for (int oo = 0; oo < 8; ++oo) {
    bool act = o == oo;
    unsigned long long mb = __ballot(act);
    int pre = __popcll(mb & ((1ull << r) - 1));
    if (act) entu[(size_t)T * 64 + base + pre] = (r << 25) | pa;
    base += __popcll(mb);
    if (r == 0) segu[T * 9 + oo + 1] = base;
  }
}

// ---------- output-stationary tiled conv: LDS accumulator, no global atomics ----------
// seg[T][KT+1] prefix offsets; ent[T*ecap] entries (r<<25 | j).
// out[T*64+r] = sum_k bnrelu(in[j]) @ W[k]  (plain float4 stores)
template <int CI, int CO, int KT, bool BN, bool CAT>
__global__ __launch_bounds__(BLK) void tconv_k(
    const float* __restrict__ inA, const float* __restrict__ inB,
    const int* __restrict__ seg, const int* __restrict__ ent, int ecap,
    const float* __restrict__ stA, const float* __restrict__ stB,
    const float* __restrict__ W, float* __restrict__ out, int n) {
  constexpr int GO = CO / 16;   // cols per thread
  constexpr int XP = CI + 4;
  constexpr int AP = CO + 4;
  __shared__ float lw[CI * CO];
  __shared__ float lx[64 * XP];
  __shared__ float lacc[64 * AP];
  int t = threadIdx.x;
  int T = blockIdx.x;
  const int* segT = seg + T * (KT + 1);
  const int* entT = ent + (size_t)T * ecap;

  for (int idx = t; idx < 64 * AP; idx += BLK) lacc[idx] = 0.f;

#pragma unroll 1
  for (int k = 0; k < KT; ++k) {
    int e0 = segT[k], e1 = segT[k + 1];
    int m = e1 - e0;
    if (m == 0) continue;  // block-uniform
    // stage W[k]
    const float4* wsrc = reinterpret_cast<const float4*>(W + (size_t)k * CI * CO);
    for (int idx = t; idx < CI * CO / 4; idx += BLK)
      reinterpret_cast<float4*>(lw)[idx] = wsrc[idx];
    // stage compacted X rows (with BN+ReLU)
    for (int idx = t; idx < m * (CI / 4); idx += BLK) {
      int p = idx / (CI / 4), c4 = idx - p * (CI / 4);
      int j = entT[e0 + p] & 0x1FFFFFF;
      int cb = c4 * 4;
      float4 x;
      const float* st;
      int cc;
      if constexpr (CAT) {
        if (cb < CI / 2) { x = *reinterpret_cast<const float4*>(inA + (size_t)j * (CI / 2) + cb); st = stA; cc = cb; }
        else             { x = *reinterpret_cast<const float4*>(inB + (size_t)j * (CI / 2) + cb - CI / 2); st = stB; cc = cb - CI / 2; }
      } else {
        x = *reinterpret_cast<const float4*>(inA + (size_t)j * CI + cb); st = stA; cc = cb;
      }
      float v[4] = {x.x, x.y, x.z, x.w};
      if constexpr (BN) {
        constexpr int SH = CAT ? CI / 2 : CI;
#pragma unroll
        for (int q = 0; q < 4; ++q) {
          float y = fmaf(v[q], st[cc + q], st[SH + cc + q]);
          v[q] = y > 0.f ? y : 0.f;
        }
      }
      *reinterpret_cast<float4*>(&lx[p * XP + cb]) = make_float4(v[0], v[1], v[2], v[3]);
    }
    __syncthreads();
    // mini-GEMM: pairs x CI x CO, accumulate into LDS acc (rows unique within k)
    int s = t >> 4, g = (t & 15) * GO;
#pragma unroll 1
    for (int p0 = 0; p0 < m; p0 += 16) {
      int p = p0 + s;
      if (p < m) {
        int r = entT[e0 + p] >> 25;
        float acc[GO];
#pragma unroll
        for (int b = 0; b < GO; ++b) acc[b] = 0.f;
#pragma unroll
        for (int c4 = 0; c4 < CI / 4; ++c4) {
          float4 xq = *reinterpret_cast<const float4*>(&lx[p * XP + c4 * 4]);
          float xs[4] = {xq.x, xq.y, xq.z, xq.w};
#pragma unroll
          for (int q = 0; q < 4; ++q) {
            const float* wr = &lw[(c4 * 4 + q) * CO + g];
            if constexpr (GO == 4) {
              float4 wv = *reinterpret_cast<const float4*>(wr);
              acc[0] = fmaf(xs[q], wv.x, acc[0]);
              acc[1] = fmaf(xs[q], wv.y, acc[1]);
              acc[2] = fmaf(xs[q], wv.z, acc[2]);
              acc[3] = fmaf(xs[q], wv.w, acc[3]);
            } else {
              float2 wv = *reinterpret_cast<const float2*>(wr);
              acc[0] = fmaf(xs[q], wv.x, acc[0]);
              acc[1] = fmaf(xs[q], wv.y, acc[1]);
            }
          }
        }
        float* ap = &lacc[r * AP + g];
        if constexpr (GO == 4) {
          float4 old = *reinterpret_cast<float4*>(ap);
          *reinterpret_cast<float4*>(ap) =
              make_float4(old.x + acc[0], old.y + acc[1], old.z + acc[2], old.w + acc[3]);
        } else {
          float2 old = *reinterpret_cast<float2*>(ap);
          *reinterpret_cast<float2*>(ap) = make_float2(old.x + acc[0], old.y + acc[1]);
        }
      }
    }
    __syncthreads();
  }
  __syncthreads();
  // epilogue: full-tile coalesced store
  for (int idx = t; idx < 64 * (CO / 4); idx += BLK) {
    int r = idx / (CO / 4), c4 = idx - r * (CO / 4);
    int row = T * 64 + r;
    if (row < n)
      *reinterpret_cast<float4*>(out + (size_t)row * CO + c4 * 4) =
          *reinterpret_cast<const float4*>(&lacc[r * AP + c4 * 4]);
  }
}

// ---------------- conv_in: [N,3] x [27,3,32] -> [N,32] (per-site gather) ----------------
__global__ __launch_bounds__(BLK) void conv_in_k(
    const float* __restrict__ feat, const int* __restrict__ nbr,
    const float* __restrict__ W, float* __restrict__ out, int n) {
  int i = blockIdx.x * BLK + threadIdx.x;
  if (i >= n) return;
  float acc[32];
#pragma unroll
  for (int c = 0; c < 32; ++c) acc[c] = 0.f;
  const int* nr = nbr + (size_t)i * 27;
#pragma unroll 1
  for (int k = 0; k < 27; ++k) {
    int j = nr[k];
    if (j < 0) continue;
    float x0 = feat[j * 3 + 0], x1 = feat[j * 3 + 1], x2 = feat[j * 3 + 2];
    const float* w0 = W + k * 96;
#pragma unroll
    for (int co = 0; co < 8; ++co) {
      float4 a = *reinterpret_cast<const float4*>(w0 + co * 4);
      float4 b = *reinterpret_cast<const float4*>(w0 + 32 + co * 4);
      float4 cc = *reinterpret_cast<const float4*>(w0 + 64 + co * 4);
      acc[4*co+0] = fmaf(x0, a.x, fmaf(x1, b.x, fmaf(x2, cc.x, acc[4*co+0])));
      acc[4*co+1] = fmaf(x0, a.y, fmaf(x1, b.y, fmaf(x2, cc.y, acc[4*co+1])));
      acc[4*co+2] = fmaf(x0, a.z, fmaf(x1, b.z, fmaf(x2, cc.z, acc[4*co+2])));
      acc[4*co+3] = fmaf(x0, a.w, fmaf(x1, b.w, fmaf(x2, cc.w, acc[4*co+3])));
    }
  }
  float* o = out + (size_t)i * 32;
#pragma unroll
  for (int co = 0; co < 8; ++co)
    *reinterpret_cast<float4*>(o + co * 4) = make_float4(acc[4*co], acc[4*co+1], acc[4*co+2], acc[4*co+3]);
}

// ---------------- per-channel sum / sumsq ----------------
template <int C>
__global__ __launch_bounds__(BLK) void stats_k(
    const float* __restrict__ f, int n, float* __restrict__ sums) {
  constexpr int G = BLK / C;
  int c = threadIdx.x % C;
  int g = threadIdx.x / C;
  float s = 0.f, ss = 0.f;
  for (int r = blockIdx.x * G + g; r < n; r += gridDim.x * G) {
    float x = f[(size_t)r * C + c];
    s += x;
    ss += x * x;
  }
  __shared__ float ls[BLK], lss[BLK];
  ls[threadIdx.x] = s;
  lss[threadIdx.x] = ss;
  __syncthreads();
  if (threadIdx.x < C) {
    float ts = 0.f, tss = 0.f;
#pragma unroll
    for (int q = 0; q < G; ++q) { ts += ls[q * C + c]; tss += lss[q * C + c]; }
    atomicAdd(&sums[c], ts);
    atomicAdd(&sums[C + c], tss);
  }
}

__global__ void finalize_k(const float* __restrict__ sums,
                           const float* __restrict__ gamma,
                           const float* __restrict__ beta, float inv_n,
                           float* __restrict__ st, int C) {
  int c = threadIdx.x;
  if (c >= C) return;
  float mu = sums[c] * inv_n;
  float var = sums[C + c] * inv_n - mu * mu;
  float sc = gamma[c] / sqrtf(var + EPS_BN);
  st[c] = sc;
  st[C + c] = beta[c] - mu * sc;
}

// ---------------- head: bn(f3) @ w_lin + b_lin -> [N,50] ----------------
__global__ __launch_bounds__(BLK) void head_k(
    const float* __restrict__ fin, const float* __restrict__ st,
    const float* __restrict__ Wl, const float* __restrict__ bl,
    float* __restrict__ out, int n) {
  __shared__ float lw[32 * 50];
  __shared__ float lb[52];
  for (int idx = threadIdx.x; idx < 1600; idx += BLK) lw[idx] = Wl[idx];
  if (threadIdx.x < 50) lb[threadIdx.x] = bl[threadIdx.x];
  __syncthreads();
  int i = blockIdx.x * BLK + threadIdx.x;
  if (i >= n) return;
  float x[32];
  const float* fj = fin + (size_t)i * 32;
#pragma unroll
  for (int c4 = 0; c4 < 8; ++c4) {
    float4 v = *reinterpret_cast<const float4*>(fj + c4 * 4);
    float vs[4] = {v.x, v.y, v.z, v.w};
#pragma unroll
    for (int q = 0; q < 4; ++q) {
      int c = c4 * 4 + q;
      float y = fmaf(vs[q], st[c], st[32 + c]);
      x[c] = y > 0.f ? y : 0.f;
    }
  }
  float acc[50];
#pragma unroll
  for (int co = 0; co < 50; ++co) acc[co] = lb[co];
#pragma unroll 4
  for (int c = 0; c < 32; ++c) {
#pragma unroll
    for (int co = 0; co < 50; ++co) acc[co] = fmaf(x[c], lw[c * 50 + co], acc[co]);
  }
  float* o = out + (size_t)i * 50;
#pragma unroll
  for (int co = 0; co < 25; ++co)
    *reinterpret_cast<float2*>(o + co * 2) = make_float2(acc[co * 2], acc[co * 2 + 1]);
}

extern "C" void kernel_launch(void* const* d_in, const int* in_sizes, int n_in,
                              void* d_out, int out_size, void* d_ws, size_t ws_size,
                              hipStream_t stream) {
  const float* feat   = (const float*)d_in[1];
  const int*   nbrF   = (const int*)d_in[2];
  const int*   nbrC   = (const int*)d_in[3];
  const int*   parent = (const int*)d_in[4];
  const int*   offid  = (const int*)d_in[5];
  const float* w_in   = (const float*)d_in[7];
  const float* w_b1   = (const float*)d_in[8];
  const float* w_down = (const float*)d_in[9];
  const float* w_b2   = (const float*)d_in[10];
  const float* w_up   = (const float*)d_in[11];
  const float* w_b3   = (const float*)d_in[12];
  const float* g1 = (const float*)d_in[13], *b1 = (const float*)d_in[14];
  const float* gd = (const float*)d_in[15], *bd = (const float*)d_in[16];
  const float* g2 = (const float*)d_in[17], *b2 = (const float*)d_in[18];
  const float* gu = (const float*)d_in[19], *bu = (const float*)d_in[20];
  const float* g3 = (const float*)d_in[21], *b3 = (const float*)d_in[22];
  const float* go = (const float*)d_in[23], *bo = (const float*)d_in[24];
  const float* w_lin = (const float*)d_in[25];
  const float* b_lin = (const float*)d_in[26];
  float* out = (float*)d_out;

  int N  = in_sizes[4];
  int NC = in_sizes[3] / 27;
  int ntF = (N + 63) / 64, ntC = (NC + 63) / 64;

  size_t szF = (size_t)N * 32;
  size_t szG = (size_t)NC * 64;
  size_t SA = szG > szF ? szG : szF;

  float* ws  = (float*)d_ws;
  float* A   = ws;              // f1 -> g2c -> f3 (lifetimes disjoint)
  float* f2  = A + SA;          // [N,32] skip
  float* gCu = f2 + szF;        // gC [NC,64] -> u [N,32]
  float* sums1 = gCu + szG;     // 64
  float* sumsD = sums1 + 64;    // 64
  float* sums2 = sumsD + 64;    // 128
  float* sumsU = sums2 + 128;   // 128
  float* sums4 = sumsU + 128;   // 64
  float* sums5 = sums4 + 64;    // 64
  float* st1  = sums5 + 64;
  float* stD  = st1 + 64;
  float* st3a = stD + 64;
  float* st2  = st3a + 64;      // 128
  float* stU  = st2 + 128;      // 128
  float* st3b = stU + 128;      // 64
  float* stO  = st3b + 64;      // 64
  int* segF = (int*)(stO + 64);               // ntF*28
  int* entF = segF + (size_t)ntF * 28;        // ntF*ECAPF
  int* segC = entF + (size_t)ntF * ECAPF;     // ntC*28
  int* entC = segC + (size_t)ntC * 28;        // ntC*ECAPC
  int* ccnt = entC + (size_t)ntC * ECAPC;     // NC
  int* cent = ccnt + NC;                      // NC*8
  int* segD = cent + (size_t)NC * 8;          // ntC*9
  int* entD = segD + (size_t)ntC * 9;         // ntC*512
  int* segU = entD + (size_t)ntC * 512;       // ntF*9
  int* entU = segU + (size_t)ntF * 9;         // ntF*64

  hipMemsetAsync(sums1, 0, 512 * sizeof(float), stream);
  hipMemsetAsync(ccnt, 0, (size_t)NC * sizeof(int), stream);

  int gridN = (N + BLK - 1) / BLK;
  int sgrid = 304;
  float invN = 1.f / (float)N, invC = 1.f / (float)NC;

  // rulebooks
  build_subm_k<<<ntF, 64, 0, stream>>>(nbrF, N, ECAPF, segF, entF);
  build_subm_k<<<ntC, 64, 0, stream>>>(nbrC, NC, ECAPC, segC, entC);
  child_scatter_k<<<gridN, BLK, 0, stream>>>(parent, offid, N, ccnt, cent);
  build_down_k<<<ntC, 64, 0, stream>>>(ccnt, cent, NC, segD, entD);
  build_up_k<<<ntF, 64, 0, stream>>>(parent, offid, N, segU, entU);

  // conv_in -> f1 (A)
  conv_in_k<<<gridN, BLK, 0, stream>>>(feat, nbrF, w_in, A, N);
  stats_k<32><<<sgrid, BLK, 0, stream>>>(A, N, sums1);
  finalize_k<<<1, 64, 0, stream>>>(sums1, g1, b1, invN, st1, 32);

  // b1 -> f2
  tconv_k<32, 32, 27, true, false><<<ntF, BLK, 0, stream>>>(
      A, nullptr, segF, entF, ECAPF, st1, nullptr, w_b1, f2, N);
  stats_k<32><<<sgrid, BLK, 0, stream>>>(f2, N, sumsD);
  finalize_k<<<1, 64, 0, stream>>>(sumsD, gd, bd, invN, stD, 32);
  finalize_k<<<1, 64, 0, stream>>>(sumsD, g3, b3, invN, st3a, 32);

  // down -> gC (full-tile stores, no memset needed)
  tconv_k<32, 64, 8, true, false><<<ntC, BLK, 0, stream>>>(
      f2, nullptr, segD, entD, 512, stD, nullptr, w_down, gCu, NC);
  stats_k<64><<<sgrid, BLK, 0, stream>>>(gCu, NC, sums2);
  finalize_k<<<1, 64, 0, stream>>>(sums2, g2, b2, invC, st2, 64);

  // b2 -> g2c (A; f1 dead)
  tconv_k<64, 64, 27, true, false><<<ntC, BLK, 0, stream>>>(
      gCu, nullptr, segC, entC, ECAPC, st2, nullptr, w_b2, A, NC);
  stats_k<64><<<sgrid, BLK, 0, stream>>>(A, NC, sumsU);
  finalize_k<<<1, 64, 0, stream>>>(sumsU, gu, bu, invC, stU, 64);

  // up -> u (gCu; gC dead)
  tconv_k<64, 32, 8, true, false><<<ntF, BLK, 0, stream>>>(
      A, nullptr, segU, entU, 64, stU, nullptr, w_up, gCu, N);
  stats_k<32><<<sgrid, BLK, 0, stream>>>(gCu, N, sums4);
  finalize_k<<<1, 64, 0, stream>>>(sums4, g3 + 32, b3 + 32, invN, st3b, 32);

  // cat conv -> f3 (A; g2c dead)
  tconv_k<64, 32, 27, true, true><<<ntF, BLK, 0, stream>>>(
      f2, gCu, segF, entF, ECAPF, st3a, st3b, w_b3, A, N);
  stats_k<32><<<sgrid, BLK, 0, stream>>>(A, N, sums5);
  finalize_k<<<1, 64, 0, stream>>>(sums5, go, bo, invN, stO, 32);

  head_k<<<gridN, BLK, 0, stream>>>(A, stO, w_lin, b_lin, out, N);
}